// Round 5
// baseline (232.896 us; speedup 1.0000x reference)
//
#include <hip/hip_runtime.h>

#define N_NODES 50000
#define NE      800000
#define NTOT    850000   // NE + N_NODES self loops
#define FDIM    128
#define OUTC    64

typedef _Float16 half4 __attribute__((ext_vector_type(4)));

// edge_index arrives as int32: [src row (NE) | dst row (NE)]

// ---------------- zero deg+cursor (replaces graph-captured hipMemsetAsync,
// which runs as a tiny-grid fillBuffer kernel at ~42 us) ----------------

__global__ __launch_bounds__(256) void k_zero(int4* __restrict__ p) {
    int i = blockIdx.x * 256 + threadIdx.x;
    if (i < 25000) p[i] = make_int4(0, 0, 0, 0);   // 100000 ints = deg + cursor
}

// ---------------- CSR build ----------------

__global__ __launch_bounds__(256) void k_count(const int* __restrict__ ei, int* __restrict__ deg) {
    int base = blockIdx.x * 1024 + threadIdx.x;
    #pragma unroll
    for (int j = 0; j < 4; ++j) {
        int e = base + j * 256;
        if (e < NE) atomicAdd(&deg[ei[NE + e]], 1);
    }
}

__global__ __launch_bounds__(1024) void k_scan1(const int* __restrict__ deg,
                                                int* __restrict__ rowptr,
                                                int* __restrict__ bsum) {
    __shared__ int wsum[16];
    int tid = threadIdx.x;
    int n = blockIdx.x * 1024 + tid;
    int v = (n < N_NODES) ? (deg[n] + 1) : 0;   // +1 = self loop
    int sc = v;
    #pragma unroll
    for (int off = 1; off < 64; off <<= 1) {
        int t = __shfl_up(sc, off);
        if ((tid & 63) >= off) sc += t;
    }
    int wave = tid >> 6;
    if ((tid & 63) == 63) wsum[wave] = sc;
    __syncthreads();
    if (tid < 16) {
        int wv = wsum[tid];
        int s2 = wv;
        #pragma unroll
        for (int off = 1; off < 16; off <<= 1) {
            int t = __shfl_up(s2, off);
            if (tid >= off) s2 += t;
        }
        wsum[tid] = s2 - wv;                    // exclusive wave offset
    }
    __syncthreads();
    if (n < N_NODES) rowptr[n] = sc - v + wsum[wave];
    if (tid == 1023) bsum[blockIdx.x] = sc + wsum[15];
}

__global__ void k_scan2(int* __restrict__ bsum, int nb) {
    int tid = threadIdx.x;      // one wave
    int v = (tid < nb) ? bsum[tid] : 0;
    int orig = v;
    #pragma unroll
    for (int off = 1; off < 64; off <<= 1) {
        int t = __shfl_up(v, off);
        if (tid >= off) v += t;
    }
    if (tid < nb) bsum[tid] = v - orig;         // exclusive
}

__global__ __launch_bounds__(256) void k_finish(const int* __restrict__ deg,
                                                int* __restrict__ rowptr,
                                                const int* __restrict__ bsum,
                                                float* __restrict__ dinv) {
    int n = blockIdx.x * 256 + threadIdx.x;
    if (n < N_NODES) {
        rowptr[n] += bsum[n >> 10];
        dinv[n] = rsqrtf((float)(deg[n] + 1));
    }
    if (n == 0) rowptr[N_NODES] = NTOT;
}

// 4 independent edge-chains per thread to hide atomic-return + scatter latency
__global__ __launch_bounds__(256) void k_fill(const int* __restrict__ ei,
                                              const int* __restrict__ rowptr,
                                              int* __restrict__ cursor,
                                              const float* __restrict__ dinv,
                                              int2* __restrict__ pk) {
    int base = blockIdx.x * 1024 + threadIdx.x;
    #pragma unroll
    for (int j = 0; j < 4; ++j) {
        int e = base + j * 256;
        if (e < NE) {
            int s = ei[e];
            int d = ei[NE + e];
            int pos = rowptr[d] + atomicAdd(&cursor[d], 1);
            pk[pos] = make_int2(s, __float_as_int(dinv[s] * dinv[d]));
        }
    }
}

__global__ __launch_bounds__(256) void k_loops(const int* __restrict__ rowptr,
                                               const float* __restrict__ dinv,
                                               int2* __restrict__ pk) {
    int n = blockIdx.x * 256 + threadIdx.x;
    if (n < N_NODES) {
        float dv = dinv[n];
        pk[rowptr[n + 1] - 1] = make_int2(n, __float_as_int(dv * dv));
    }
}

// ---------------- fp32 -> fp16 convert (x) ----------------

__global__ __launch_bounds__(256) void k_cvt(const float* __restrict__ in,
                                             _Float16* __restrict__ out) {
    int i = blockIdx.x * 256 + threadIdx.x;     // quad index
    if (i < (N_NODES * FDIM) / 4) {
        float4 v = reinterpret_cast<const float4*>(in)[i];
        half4 h = {(_Float16)v.x, (_Float16)v.y, (_Float16)v.z, (_Float16)v.w};
        reinterpret_cast<half4*>(out)[i] = h;
    }
}

// ---------------- aggregation (fp16 in, fp32 out) ----------------

__device__ __forceinline__ float4 fma4h(float s, half4 h, float4 a) {
    a.x = fmaf(s, (float)h.x, a.x); a.y = fmaf(s, (float)h.y, a.y);
    a.z = fmaf(s, (float)h.z, a.z); a.w = fmaf(s, (float)h.w, a.w);
    return a;
}

__global__ __launch_bounds__(256) void k_agg(const _Float16* __restrict__ in,
                                             float* __restrict__ out,
                                             const int* __restrict__ rowptr,
                                             const int2* __restrict__ pk) {
    int tid  = threadIdx.x;
    int r    = blockIdx.x * 8 + (tid >> 5);
    if (r >= N_NODES) return;
    int lane4 = (tid & 31) * 4;
    int start = rowptr[r], end = rowptr[r + 1];
    float4 a0 = {0,0,0,0}, a1 = {0,0,0,0}, a2 = {0,0,0,0}, a3 = {0,0,0,0};
    int e = start;
    for (; e + 4 <= end; e += 4) {
        int2 p0 = pk[e], p1 = pk[e + 1], p2 = pk[e + 2], p3 = pk[e + 3];
        half4 x0 = *reinterpret_cast<const half4*>(&in[(size_t)p0.x * FDIM + lane4]);
        half4 x1 = *reinterpret_cast<const half4*>(&in[(size_t)p1.x * FDIM + lane4]);
        half4 x2 = *reinterpret_cast<const half4*>(&in[(size_t)p2.x * FDIM + lane4]);
        half4 x3 = *reinterpret_cast<const half4*>(&in[(size_t)p3.x * FDIM + lane4]);
        a0 = fma4h(__int_as_float(p0.y), x0, a0);
        a1 = fma4h(__int_as_float(p1.y), x1, a1);
        a2 = fma4h(__int_as_float(p2.y), x2, a2);
        a3 = fma4h(__int_as_float(p3.y), x3, a3);
    }
    for (; e < end; ++e) {
        int2 p = pk[e];
        half4 xv = *reinterpret_cast<const half4*>(&in[(size_t)p.x * FDIM + lane4]);
        a0 = fma4h(__int_as_float(p.y), xv, a0);
    }
    float4 acc;
    acc.x = (a0.x + a1.x) + (a2.x + a3.x);
    acc.y = (a0.y + a1.y) + (a2.y + a3.y);
    acc.z = (a0.z + a1.z) + (a2.z + a3.z);
    acc.w = (a0.w + a1.w) + (a2.w + a3.w);
    *reinterpret_cast<float4*>(&out[(size_t)r * FDIM + lane4]) = acc;
}

// ---------------- GEMMs: 64-row tile, 8x4 register tile, [m][k] LDS ----------------

__device__ __forceinline__ float4 fma4(float s, float4 w, float4 a) {
    a.x = fmaf(s, w.x, a.x); a.y = fmaf(s, w.y, a.y);
    a.z = fmaf(s, w.z, a.z); a.w = fmaf(s, w.w, a.w);
    return a;
}

#define LDK 132   // 128 + 4 pad, keeps rows 16B-aligned

// h = relu(A @ W + b)  -> stored as fp16 (feeds second aggregation)
__global__ __launch_bounds__(256) void k_gemm_relu(const float* __restrict__ A,
                                                   const float* __restrict__ W,
                                                   const float* __restrict__ b,
                                                   _Float16* __restrict__ out) {
    __shared__ float xs[64][LDK];
    int tid = threadIdx.x;
    int m0 = blockIdx.x * 64;
    #pragma unroll
    for (int i = 0; i < 8; ++i) {
        int lin = i * 256 + tid;                // 0..2047
        int m = lin >> 5;                       // 0..63
        int kq = (lin & 31) << 2;               // 0,4,...,124
        int mm = m0 + m;
        float4 v = {0.f, 0.f, 0.f, 0.f};
        if (mm < N_NODES) v = *reinterpret_cast<const float4*>(&A[(size_t)mm * FDIM + kq]);
        *reinterpret_cast<float4*>(&xs[m][kq]) = v;
    }
    __syncthreads();
    int tx = tid & 31, ty = tid >> 5;
    int n0 = tx * 4, mr = ty * 8;
    float4 acc[8];
    #pragma unroll
    for (int i = 0; i < 8; ++i) acc[i] = make_float4(0.f, 0.f, 0.f, 0.f);
    for (int k = 0; k < 128; k += 4) {
        float4 w0 = *reinterpret_cast<const float4*>(&W[(k + 0) * 128 + n0]);
        float4 w1 = *reinterpret_cast<const float4*>(&W[(k + 1) * 128 + n0]);
        float4 w2 = *reinterpret_cast<const float4*>(&W[(k + 2) * 128 + n0]);
        float4 w3 = *reinterpret_cast<const float4*>(&W[(k + 3) * 128 + n0]);
        #pragma unroll
        for (int i = 0; i < 8; ++i) {
            float4 xk = *reinterpret_cast<const float4*>(&xs[mr + i][k]);  // broadcast
            acc[i] = fma4(xk.x, w0, acc[i]);
            acc[i] = fma4(xk.y, w1, acc[i]);
            acc[i] = fma4(xk.z, w2, acc[i]);
            acc[i] = fma4(xk.w, w3, acc[i]);
        }
    }
    float4 bias = *reinterpret_cast<const float4*>(&b[n0]);
    #pragma unroll
    for (int i = 0; i < 8; ++i) {
        int m = m0 + mr + i;
        if (m < N_NODES) {
            half4 o = {(_Float16)fmaxf(acc[i].x + bias.x, 0.f),
                       (_Float16)fmaxf(acc[i].y + bias.y, 0.f),
                       (_Float16)fmaxf(acc[i].z + bias.z, 0.f),
                       (_Float16)fmaxf(acc[i].w + bias.w, 0.f)};
            *reinterpret_cast<half4*>(&out[(size_t)m * FDIM + n0]) = o;
        }
    }
}

// fused: [mu|ls] = A @ [Wmu|Wls] + [bmu|bls]
__global__ __launch_bounds__(256) void k_gemm_out(const float* __restrict__ A,
                                                  const float* __restrict__ Wmu,
                                                  const float* __restrict__ bmu,
                                                  const float* __restrict__ Wls,
                                                  const float* __restrict__ bls,
                                                  float* __restrict__ outmu,
                                                  float* __restrict__ outls) {
    __shared__ float xs[64][LDK];
    int tid = threadIdx.x;
    int m0 = blockIdx.x * 64;
    #pragma unroll
    for (int i = 0; i < 8; ++i) {
        int lin = i * 256 + tid;
        int m = lin >> 5;
        int kq = (lin & 31) << 2;
        int mm = m0 + m;
        float4 v = {0.f, 0.f, 0.f, 0.f};
        if (mm < N_NODES) v = *reinterpret_cast<const float4*>(&A[(size_t)mm * FDIM + kq]);
        *reinterpret_cast<float4*>(&xs[m][kq]) = v;
    }
    __syncthreads();
    int tx = tid & 31, ty = tid >> 5;
    int n0 = tx * 4, mr = ty * 8;
    bool is_mu = (n0 < 64);
    const float* Wp = is_mu ? (Wmu + n0) : (Wls + (n0 - 64));
    const float* bp = is_mu ? (bmu + n0) : (bls + (n0 - 64));
    float* op       = is_mu ? outmu : outls;
    int nc          = is_mu ? n0 : (n0 - 64);
    float4 acc[8];
    #pragma unroll
    for (int i = 0; i < 8; ++i) acc[i] = make_float4(0.f, 0.f, 0.f, 0.f);
    for (int k = 0; k < 128; k += 4) {
        float4 w0 = *reinterpret_cast<const float4*>(&Wp[(k + 0) * 64]);
        float4 w1 = *reinterpret_cast<const float4*>(&Wp[(k + 1) * 64]);
        float4 w2 = *reinterpret_cast<const float4*>(&Wp[(k + 2) * 64]);
        float4 w3 = *reinterpret_cast<const float4*>(&Wp[(k + 3) * 64]);
        #pragma unroll
        for (int i = 0; i < 8; ++i) {
            float4 xk = *reinterpret_cast<const float4*>(&xs[mr + i][k]);
            acc[i] = fma4(xk.x, w0, acc[i]);
            acc[i] = fma4(xk.y, w1, acc[i]);
            acc[i] = fma4(xk.z, w2, acc[i]);
            acc[i] = fma4(xk.w, w3, acc[i]);
        }
    }
    float4 bias = *reinterpret_cast<const float4*>(bp);
    #pragma unroll
    for (int i = 0; i < 8; ++i) {
        int m = m0 + mr + i;
        if (m < N_NODES) {
            float4 o;
            o.x = acc[i].x + bias.x;
            o.y = acc[i].y + bias.y;
            o.z = acc[i].z + bias.z;
            o.w = acc[i].w + bias.w;
            *reinterpret_cast<float4*>(&op[(size_t)m * OUTC + nc]) = o;
        }
    }
}

// ---------------- launch ----------------

extern "C" void kernel_launch(void* const* d_in, const int* in_sizes, int n_in,
                              void* d_out, int out_size, void* d_ws, size_t ws_size,
                              hipStream_t stream) {
    const float* x   = (const float*)d_in[0];
    const int*   ei  = (const int*)d_in[1];
    const float* W1  = (const float*)d_in[2];
    const float* b1  = (const float*)d_in[3];
    const float* Wmu = (const float*)d_in[4];
    const float* bmu = (const float*)d_in[5];
    const float* Wls = (const float*)d_in[6];
    const float* bls = (const float*)d_in[7];
    float* out = (float*)d_out;

    char* ws = (char*)d_ws;
    int*   deg    = (int*)  (ws + 0);         //  50000 ints
    int*   cursor = (int*)  (ws + 200000);    //  50000 ints
    int*   rowptr = (int*)  (ws + 400000);    //  50001 ints
    int*   bsum   = (int*)  (ws + 600064);    //     64 ints
    float* dinv   = (float*)(ws + 600320);    //  50000 floats
    int2*  pk     = (int2*) (ws + 800320);    // 850000 int2
    float* buf1   = (float*)(ws + 7600320);   // 6.4M floats (agg result)

    // fp16 staging lives in d_out (12.8 MB of its 25.6 MB), time-shared:
    //   k_cvt writes x16 -> agg1 reads it -> gemm1 overwrites with h16 ->
    //   agg2 reads h16 -> gemm_out overwrites d_out with final [mu|ls].
    _Float16* f16buf = (_Float16*)d_out;

    k_zero  <<<98, 256, 0, stream>>>((int4*)ws);   // deg + cursor (100000 ints)
    k_cvt   <<<(N_NODES * FDIM / 4 + 255) / 256, 256, 0, stream>>>(x, f16buf);
    k_count <<<(NE + 1023) / 1024, 256, 0, stream>>>(ei, deg);
    k_scan1 <<<49, 1024, 0, stream>>>(deg, rowptr, bsum);
    k_scan2 <<<1, 64, 0, stream>>>(bsum, 49);
    k_finish<<<(N_NODES + 255) / 256, 256, 0, stream>>>(deg, rowptr, bsum, dinv);
    k_fill  <<<(NE + 1023) / 1024, 256, 0, stream>>>(ei, rowptr, cursor, dinv, pk);
    k_loops <<<(N_NODES + 255) / 256, 256, 0, stream>>>(rowptr, dinv, pk);

    // layer 1
    k_agg      <<<N_NODES / 8, 256, 0, stream>>>(f16buf, buf1, rowptr, pk);
    k_gemm_relu<<<(N_NODES + 63) / 64, 256, 0, stream>>>(buf1, W1, b1, f16buf);

    // layer 2
    k_agg     <<<N_NODES / 8, 256, 0, stream>>>(f16buf, buf1, rowptr, pk);
    k_gemm_out<<<(N_NODES + 63) / 64, 256, 0, stream>>>(buf1, Wmu, bmu, Wls, bls,
                                                        out, out + (size_t)N_NODES * OUTC);
}

// Round 6
// 199.177 us; speedup vs baseline: 1.1693x; 1.1693x over previous
//
#include <hip/hip_runtime.h>

#define N_NODES 50000
#define NE      800000
#define NTOT    850000   // NE + N_NODES self loops
#define FDIM    128
#define OUTC    64

typedef _Float16 half4 __attribute__((ext_vector_type(4)));

// edge_index arrives as int32: [src row (NE) | dst row (NE)]

// ---------------- prep: zero deg (blocks 0..48) + fp32->fp16 cvt of x ----------------

__global__ __launch_bounds__(256) void k_prep(const float* __restrict__ in,
                                              _Float16* __restrict__ out,
                                              int4* __restrict__ deg4) {
    int b = blockIdx.x;
    if (b < 49) {
        int i = b * 256 + threadIdx.x;
        if (i < 12500) deg4[i] = make_int4(0, 0, 0, 0);   // 50000 ints
    } else {
        int i = (b - 49) * 256 + threadIdx.x;             // quad index
        if (i < (N_NODES * FDIM) / 4) {
            float4 v = reinterpret_cast<const float4*>(in)[i];
            half4 h = {(_Float16)v.x, (_Float16)v.y, (_Float16)v.z, (_Float16)v.w};
            reinterpret_cast<half4*>(out)[i] = h;
        }
    }
}

// ---------------- CSR build ----------------
// count AND capture each edge's slot within its dst row (atomic return value)
__global__ __launch_bounds__(256) void k_count(const int* __restrict__ ei,
                                               int* __restrict__ deg,
                                               int* __restrict__ slot) {
    int e = blockIdx.x * 256 + threadIdx.x;
    if (e < NE) slot[e] = atomicAdd(&deg[ei[NE + e]], 1);
}

__global__ __launch_bounds__(1024) void k_scan1(const int* __restrict__ deg,
                                                int* __restrict__ rowptr,
                                                int* __restrict__ bsum) {
    __shared__ int wsum[16];
    int tid = threadIdx.x;
    int n = blockIdx.x * 1024 + tid;
    int v = (n < N_NODES) ? (deg[n] + 1) : 0;   // +1 = self loop
    int sc = v;
    #pragma unroll
    for (int off = 1; off < 64; off <<= 1) {
        int t = __shfl_up(sc, off);
        if ((tid & 63) >= off) sc += t;
    }
    int wave = tid >> 6;
    if ((tid & 63) == 63) wsum[wave] = sc;
    __syncthreads();
    if (tid < 16) {
        int wv = wsum[tid];
        int s2 = wv;
        #pragma unroll
        for (int off = 1; off < 16; off <<= 1) {
            int t = __shfl_up(s2, off);
            if (tid >= off) s2 += t;
        }
        wsum[tid] = s2 - wv;                    // exclusive wave offset
    }
    __syncthreads();
    if (n < N_NODES) rowptr[n] = sc - v + wsum[wave];
    if (tid == 1023) bsum[blockIdx.x] = sc + wsum[15];
}

__global__ void k_scan2(int* __restrict__ bsum, int nb) {
    int tid = threadIdx.x;      // one wave
    int v = (tid < nb) ? bsum[tid] : 0;
    int orig = v;
    #pragma unroll
    for (int off = 1; off < 64; off <<= 1) {
        int t = __shfl_up(v, off);
        if (tid >= off) v += t;
    }
    if (tid < nb) bsum[tid] = v - orig;         // exclusive
}

__global__ __launch_bounds__(256) void k_finish(const int* __restrict__ deg,
                                                int* __restrict__ rowptr,
                                                const int* __restrict__ bsum,
                                                float* __restrict__ dinv) {
    int n = blockIdx.x * 256 + threadIdx.x;
    if (n < N_NODES) {
        rowptr[n] += bsum[n >> 10];
        dinv[n] = rsqrtf((float)(deg[n] + 1));
    }
    if (n == 0) rowptr[N_NODES] = NTOT;
}

// atomic-free fill: pos = rowptr[d] + precomputed slot; self-loops in tail range
__global__ __launch_bounds__(256) void k_fill(const int* __restrict__ ei,
                                              const int* __restrict__ rowptr,
                                              const int* __restrict__ slot,
                                              const float* __restrict__ dinv,
                                              int2* __restrict__ pk) {
    int e = blockIdx.x * 256 + threadIdx.x;
    if (e < NE) {
        int s = ei[e];
        int d = ei[NE + e];
        pk[rowptr[d] + slot[e]] = make_int2(s, __float_as_int(dinv[s] * dinv[d]));
    } else if (e < NTOT) {
        int n = e - NE;
        float dv = dinv[n];
        pk[rowptr[n + 1] - 1] = make_int2(n, __float_as_int(dv * dv));
    }
}

// ---------------- aggregation (fp16 in, fp32 out) ----------------

__device__ __forceinline__ float4 fma4h(float s, half4 h, float4 a) {
    a.x = fmaf(s, (float)h.x, a.x); a.y = fmaf(s, (float)h.y, a.y);
    a.z = fmaf(s, (float)h.z, a.z); a.w = fmaf(s, (float)h.w, a.w);
    return a;
}

__global__ __launch_bounds__(256) void k_agg(const _Float16* __restrict__ in,
                                             float* __restrict__ out,
                                             const int* __restrict__ rowptr,
                                             const int2* __restrict__ pk) {
    int tid  = threadIdx.x;
    int r    = blockIdx.x * 8 + (tid >> 5);
    if (r >= N_NODES) return;
    int lane4 = (tid & 31) * 4;
    int start = rowptr[r], end = rowptr[r + 1];
    float4 a0 = {0,0,0,0}, a1 = {0,0,0,0}, a2 = {0,0,0,0}, a3 = {0,0,0,0};
    int e = start;
    for (; e + 4 <= end; e += 4) {
        int2 p0 = pk[e], p1 = pk[e + 1], p2 = pk[e + 2], p3 = pk[e + 3];
        half4 x0 = *reinterpret_cast<const half4*>(&in[(size_t)p0.x * FDIM + lane4]);
        half4 x1 = *reinterpret_cast<const half4*>(&in[(size_t)p1.x * FDIM + lane4]);
        half4 x2 = *reinterpret_cast<const half4*>(&in[(size_t)p2.x * FDIM + lane4]);
        half4 x3 = *reinterpret_cast<const half4*>(&in[(size_t)p3.x * FDIM + lane4]);
        a0 = fma4h(__int_as_float(p0.y), x0, a0);
        a1 = fma4h(__int_as_float(p1.y), x1, a1);
        a2 = fma4h(__int_as_float(p2.y), x2, a2);
        a3 = fma4h(__int_as_float(p3.y), x3, a3);
    }
    for (; e < end; ++e) {
        int2 p = pk[e];
        half4 xv = *reinterpret_cast<const half4*>(&in[(size_t)p.x * FDIM + lane4]);
        a0 = fma4h(__int_as_float(p.y), xv, a0);
    }
    float4 acc;
    acc.x = (a0.x + a1.x) + (a2.x + a3.x);
    acc.y = (a0.y + a1.y) + (a2.y + a3.y);
    acc.z = (a0.z + a1.z) + (a2.z + a3.z);
    acc.w = (a0.w + a1.w) + (a2.w + a3.w);
    *reinterpret_cast<float4*>(&out[(size_t)r * FDIM + lane4]) = acc;
}

// ---------------- GEMMs: 64-row tile, 8x4 register tile, [m][k] LDS ----------------

__device__ __forceinline__ float4 fma4(float s, float4 w, float4 a) {
    a.x = fmaf(s, w.x, a.x); a.y = fmaf(s, w.y, a.y);
    a.z = fmaf(s, w.z, a.z); a.w = fmaf(s, w.w, a.w);
    return a;
}

#define LDK 132   // 128 + 4 pad, keeps rows 16B-aligned

// h = relu(A @ W + b)  -> stored as fp16 (feeds second aggregation)
__global__ __launch_bounds__(256) void k_gemm_relu(const float* __restrict__ A,
                                                   const float* __restrict__ W,
                                                   const float* __restrict__ b,
                                                   _Float16* __restrict__ out) {
    __shared__ float xs[64][LDK];
    int tid = threadIdx.x;
    int m0 = blockIdx.x * 64;
    #pragma unroll
    for (int i = 0; i < 8; ++i) {
        int lin = i * 256 + tid;                // 0..2047
        int m = lin >> 5;                       // 0..63
        int kq = (lin & 31) << 2;               // 0,4,...,124
        int mm = m0 + m;
        float4 v = {0.f, 0.f, 0.f, 0.f};
        if (mm < N_NODES) v = *reinterpret_cast<const float4*>(&A[(size_t)mm * FDIM + kq]);
        *reinterpret_cast<float4*>(&xs[m][kq]) = v;
    }
    __syncthreads();
    int tx = tid & 31, ty = tid >> 5;
    int n0 = tx * 4, mr = ty * 8;
    float4 acc[8];
    #pragma unroll
    for (int i = 0; i < 8; ++i) acc[i] = make_float4(0.f, 0.f, 0.f, 0.f);
    for (int k = 0; k < 128; k += 4) {
        float4 w0 = *reinterpret_cast<const float4*>(&W[(k + 0) * 128 + n0]);
        float4 w1 = *reinterpret_cast<const float4*>(&W[(k + 1) * 128 + n0]);
        float4 w2 = *reinterpret_cast<const float4*>(&W[(k + 2) * 128 + n0]);
        float4 w3 = *reinterpret_cast<const float4*>(&W[(k + 3) * 128 + n0]);
        #pragma unroll
        for (int i = 0; i < 8; ++i) {
            float4 xk = *reinterpret_cast<const float4*>(&xs[mr + i][k]);  // broadcast
            acc[i] = fma4(xk.x, w0, acc[i]);
            acc[i] = fma4(xk.y, w1, acc[i]);
            acc[i] = fma4(xk.z, w2, acc[i]);
            acc[i] = fma4(xk.w, w3, acc[i]);
        }
    }
    float4 bias = *reinterpret_cast<const float4*>(&b[n0]);
    #pragma unroll
    for (int i = 0; i < 8; ++i) {
        int m = m0 + mr + i;
        if (m < N_NODES) {
            half4 o = {(_Float16)fmaxf(acc[i].x + bias.x, 0.f),
                       (_Float16)fmaxf(acc[i].y + bias.y, 0.f),
                       (_Float16)fmaxf(acc[i].z + bias.z, 0.f),
                       (_Float16)fmaxf(acc[i].w + bias.w, 0.f)};
            *reinterpret_cast<half4*>(&out[(size_t)m * FDIM + n0]) = o;
        }
    }
}

// fused: [mu|ls] = A @ [Wmu|Wls] + [bmu|bls]
__global__ __launch_bounds__(256) void k_gemm_out(const float* __restrict__ A,
                                                  const float* __restrict__ Wmu,
                                                  const float* __restrict__ bmu,
                                                  const float* __restrict__ Wls,
                                                  const float* __restrict__ bls,
                                                  float* __restrict__ outmu,
                                                  float* __restrict__ outls) {
    __shared__ float xs[64][LDK];
    int tid = threadIdx.x;
    int m0 = blockIdx.x * 64;
    #pragma unroll
    for (int i = 0; i < 8; ++i) {
        int lin = i * 256 + tid;
        int m = lin >> 5;
        int kq = (lin & 31) << 2;
        int mm = m0 + m;
        float4 v = {0.f, 0.f, 0.f, 0.f};
        if (mm < N_NODES) v = *reinterpret_cast<const float4*>(&A[(size_t)mm * FDIM + kq]);
        *reinterpret_cast<float4*>(&xs[m][kq]) = v;
    }
    __syncthreads();
    int tx = tid & 31, ty = tid >> 5;
    int n0 = tx * 4, mr = ty * 8;
    bool is_mu = (n0 < 64);
    const float* Wp = is_mu ? (Wmu + n0) : (Wls + (n0 - 64));
    const float* bp = is_mu ? (bmu + n0) : (bls + (n0 - 64));
    float* op       = is_mu ? outmu : outls;
    int nc          = is_mu ? n0 : (n0 - 64);
    float4 acc[8];
    #pragma unroll
    for (int i = 0; i < 8; ++i) acc[i] = make_float4(0.f, 0.f, 0.f, 0.f);
    for (int k = 0; k < 128; k += 4) {
        float4 w0 = *reinterpret_cast<const float4*>(&Wp[(k + 0) * 64]);
        float4 w1 = *reinterpret_cast<const float4*>(&Wp[(k + 1) * 64]);
        float4 w2 = *reinterpret_cast<const float4*>(&Wp[(k + 2) * 64]);
        float4 w3 = *reinterpret_cast<const float4*>(&Wp[(k + 3) * 64]);
        #pragma unroll
        for (int i = 0; i < 8; ++i) {
            float4 xk = *reinterpret_cast<const float4*>(&xs[mr + i][k]);
            acc[i] = fma4(xk.x, w0, acc[i]);
            acc[i] = fma4(xk.y, w1, acc[i]);
            acc[i] = fma4(xk.z, w2, acc[i]);
            acc[i] = fma4(xk.w, w3, acc[i]);
        }
    }
    float4 bias = *reinterpret_cast<const float4*>(bp);
    #pragma unroll
    for (int i = 0; i < 8; ++i) {
        int m = m0 + mr + i;
        if (m < N_NODES) {
            float4 o;
            o.x = acc[i].x + bias.x;
            o.y = acc[i].y + bias.y;
            o.z = acc[i].z + bias.z;
            o.w = acc[i].w + bias.w;
            *reinterpret_cast<float4*>(&op[(size_t)m * OUTC + nc]) = o;
        }
    }
}

// ---------------- launch ----------------

extern "C" void kernel_launch(void* const* d_in, const int* in_sizes, int n_in,
                              void* d_out, int out_size, void* d_ws, size_t ws_size,
                              hipStream_t stream) {
    const float* x   = (const float*)d_in[0];
    const int*   ei  = (const int*)d_in[1];
    const float* W1  = (const float*)d_in[2];
    const float* b1  = (const float*)d_in[3];
    const float* Wmu = (const float*)d_in[4];
    const float* bmu = (const float*)d_in[5];
    const float* Wls = (const float*)d_in[6];
    const float* bls = (const float*)d_in[7];
    float* out = (float*)d_out;

    char* ws = (char*)d_ws;
    int*   deg    = (int*)  (ws + 0);         //  50000 ints
    int*   rowptr = (int*)  (ws + 200000);    //  50001 ints
    int*   bsum   = (int*)  (ws + 400064);    //     64 ints
    float* dinv   = (float*)(ws + 400320);    //  50000 floats
    int2*  pk     = (int2*) (ws + 600320);    // 850000 int2
    float* buf1   = (float*)(ws + 7400320);   // 6.4M floats (agg result)
    int*   slot   = (int*)  (ws + 7400320);   // 800000 ints, aliases buf1 head
    // (slot dead once k_fill completes; buf1 first written by k_agg afterwards)

    // fp16 staging lives in d_out (12.8 MB of its 25.6 MB), time-shared:
    //   k_prep writes x16 -> agg1 reads it -> gemm1 overwrites with h16 ->
    //   agg2 reads h16 -> gemm_out overwrites d_out with final [mu|ls].
    _Float16* f16buf = (_Float16*)d_out;

    k_prep  <<<49 + (N_NODES * FDIM / 4 + 255) / 256, 256, 0, stream>>>(x, f16buf, (int4*)deg);
    k_count <<<(NE + 255) / 256, 256, 0, stream>>>(ei, deg, slot);
    k_scan1 <<<49, 1024, 0, stream>>>(deg, rowptr, bsum);
    k_scan2 <<<1, 64, 0, stream>>>(bsum, 49);
    k_finish<<<(N_NODES + 255) / 256, 256, 0, stream>>>(deg, rowptr, bsum, dinv);
    k_fill  <<<(NTOT + 255) / 256, 256, 0, stream>>>(ei, rowptr, slot, dinv, pk);

    // layer 1
    k_agg      <<<N_NODES / 8, 256, 0, stream>>>(f16buf, buf1, rowptr, pk);
    k_gemm_relu<<<(N_NODES + 63) / 64, 256, 0, stream>>>(buf1, W1, b1, f16buf);

    // layer 2
    k_agg     <<<N_NODES / 8, 256, 0, stream>>>(f16buf, buf1, rowptr, pk);
    k_gemm_out<<<(N_NODES + 63) / 64, 256, 0, stream>>>(buf1, Wmu, bmu, Wls, bls,
                                                        out, out + (size_t)N_NODES * OUTC);
}